// Round 1
// baseline (1071.775 us; speedup 1.0000x reference)
//
#include <hip/hip_runtime.h>
#include <math.h>

// Fused ECG-GAT: 2 GAT layers (fully-connected 12-node graphs) + mean-pool + MLP.
// fp32 baseline, one kernel launch, G=2 graphs per 256-thread block.

constexpr int G    = 2;    // graphs per block
constexpr int NN   = 12;   // nodes per graph
constexpr int FIN  = 128;  // input features
constexpr int C1   = 256;  // layer-1 out channels (4 heads * 64)
constexpr int HEADS= 4;
constexpr int DD   = 64;   // per-head dim / layer-2 dim
#define NEG 0.2f

__global__ __launch_bounds__(256, 3) void gat_fused(
    const float* __restrict__ x_in,   // [B][12][128]
    const float* __restrict__ W1,     // [128][256]
    const float* __restrict__ asrc1,  // [4][64]
    const float* __restrict__ adst1,  // [4][64]
    const float* __restrict__ b1,     // [256]
    const float* __restrict__ W2,     // [256][64]
    const float* __restrict__ asrc2,  // [64]
    const float* __restrict__ adst2,  // [64]
    const float* __restrict__ b2,     // [64]
    const float* __restrict__ Wc1,    // [64][32]
    const float* __restrict__ bc1,    // [32]
    const float* __restrict__ Wc2,    // [32]
    const float* __restrict__ bc2,    // [1]
    float* __restrict__ out)          // [B]
{
    // Region 1: h1 (later x2 in-place, column-exclusive update)  24 KB
    __shared__ __align__(16) float s_h1[G][NN][C1];
    // Region 2: x tile in phase A (12 KB); h2 [G][12][64] (6 KB) afterwards
    __shared__ __align__(16) float s_buf[G * NN * FIN];
    // Small arrays
    __shared__ __align__(16) float s_alpha[G][HEADS][NN][NN];
    __shared__ float s_es[G][HEADS][NN];
    __shared__ float s_ed[G][HEADS][NN];
    __shared__ __align__(16) float s_alpha2[G][NN][NN];
    __shared__ float s_es2[G][NN];
    __shared__ float s_ed2[G][NN];
    __shared__ float s_gmean[G][DD];
    __shared__ float s_hc[G][32];

    const int t = threadIdx.x;
    const long b0 = (long)blockIdx.x * G;

    // ---------------- load x tile (G*12*128 floats = 768 float4) ----------------
    {
        const float4* src = reinterpret_cast<const float4*>(x_in + b0 * NN * FIN);
        float4* dst = reinterpret_cast<float4*>(s_buf);
        #pragma unroll
        for (int j = 0; j < 3; ++j) dst[j * 256 + t] = src[j * 256 + t];
    }
    __syncthreads();

    // ---------------- Phase A: h1 = x @ W1  (weight-stationary, 2 cols/thread) ----
    {
        const int half = t >> 7;      // n-half: rows half*6 .. half*6+5
        const int cc   = t & 127;     // column-pair index
        const int c0   = cc * 2;
        float acc[G][6][2];
        #pragma unroll
        for (int g = 0; g < G; ++g)
            #pragma unroll
            for (int nl = 0; nl < 6; ++nl) { acc[g][nl][0] = 0.f; acc[g][nl][1] = 0.f; }

        for (int k0 = 0; k0 < FIN; k0 += 8) {
            float2 w[8];
            #pragma unroll
            for (int kk = 0; kk < 8; ++kk)
                w[kk] = *reinterpret_cast<const float2*>(W1 + (k0 + kk) * C1 + c0);
            #pragma unroll
            for (int g = 0; g < G; ++g) {
                #pragma unroll
                for (int nl = 0; nl < 6; ++nl) {
                    const float* xr = s_buf + ((g * NN) + half * 6 + nl) * FIN + k0;
                    float4 xa = *reinterpret_cast<const float4*>(xr);
                    float4 xb = *reinterpret_cast<const float4*>(xr + 4);
                    float a0 = acc[g][nl][0], a1 = acc[g][nl][1];
                    a0 = fmaf(xa.x, w[0].x, a0); a1 = fmaf(xa.x, w[0].y, a1);
                    a0 = fmaf(xa.y, w[1].x, a0); a1 = fmaf(xa.y, w[1].y, a1);
                    a0 = fmaf(xa.z, w[2].x, a0); a1 = fmaf(xa.z, w[2].y, a1);
                    a0 = fmaf(xa.w, w[3].x, a0); a1 = fmaf(xa.w, w[3].y, a1);
                    a0 = fmaf(xb.x, w[4].x, a0); a1 = fmaf(xb.x, w[4].y, a1);
                    a0 = fmaf(xb.y, w[5].x, a0); a1 = fmaf(xb.y, w[5].y, a1);
                    a0 = fmaf(xb.z, w[6].x, a0); a1 = fmaf(xb.z, w[6].y, a1);
                    a0 = fmaf(xb.w, w[7].x, a0); a1 = fmaf(xb.w, w[7].y, a1);
                    acc[g][nl][0] = a0; acc[g][nl][1] = a1;
                }
            }
        }
        #pragma unroll
        for (int g = 0; g < G; ++g)
            #pragma unroll
            for (int nl = 0; nl < 6; ++nl)
                *reinterpret_cast<float2*>(&s_h1[g][half * 6 + nl][c0]) =
                    make_float2(acc[g][nl][0], acc[g][nl][1]);
    }
    __syncthreads();

    // ---------------- Phase B: es/ed attention logits (192 tasks) ----------------
    if (t < G * 2 * HEADS * NN) {
        int tmp = t;
        const int n = tmp % NN; tmp /= NN;
        const int h = tmp % HEADS; tmp /= HEADS;
        const int sflag = tmp & 1;
        const int g = tmp >> 1;
        const float* att = (sflag ? adst1 : asrc1) + h * DD;
        const float* row = &s_h1[g][n][h * DD];
        float sum = 0.f;
        #pragma unroll
        for (int it = 0; it < 16; ++it) {               // rotated chunk order:
            const int dch = ((it + t) & 15) * 4;        // avoids same-bank serialization
            float4 hv = *reinterpret_cast<const float4*>(row + dch);
            float4 av = *reinterpret_cast<const float4*>(att + dch);
            sum += hv.x * av.x + hv.y * av.y + hv.z * av.z + hv.w * av.w;
        }
        if (sflag) s_ed[g][h][n] = sum; else s_es[g][h][n] = sum;
    }
    __syncthreads();

    // ---------------- Phase C: softmax over sources (96 tasks) ----------------
    if (t < G * HEADS * NN) {
        const int i = t % NN;
        const int h = (t / NN) % HEADS;
        const int g = t / (NN * HEADS);
        const float edv = s_ed[g][h][i];
        float l[NN];
        float m = -3.4e38f;
        #pragma unroll
        for (int j = 0; j < NN; ++j) {
            float v = edv + s_es[g][h][j];
            v = (v >= 0.f) ? v : NEG * v;
            l[j] = v; m = fmaxf(m, v);
        }
        float s = 0.f;
        #pragma unroll
        for (int j = 0; j < NN; ++j) { float p = expf(l[j] - m); l[j] = p; s += p; }
        const float inv = 1.f / s;
        #pragma unroll
        for (int j = 0; j < NN; ++j) s_alpha[g][h][i][j] = l[j] * inv;
    }
    __syncthreads();

    // ---------------- Phase D: out1 = alpha @ h1, +b1, elu -> x2 (in place) ------
    {
        const int c = t;
        const int hh = c >> 6;            // head, uniform per wave
        const float bias = b1[c];
        #pragma unroll
        for (int g = 0; g < G; ++g) {
            float hcol[NN];
            #pragma unroll
            for (int j = 0; j < NN; ++j) hcol[j] = s_h1[g][j][c];
            float x2v[NN];
            #pragma unroll
            for (int i = 0; i < NN; ++i) {
                const float4* ar = reinterpret_cast<const float4*>(&s_alpha[g][hh][i][0]);
                float4 q0 = ar[0], q1 = ar[1], q2 = ar[2];
                float o = q0.x * hcol[0] + q0.y * hcol[1] + q0.z * hcol[2] + q0.w * hcol[3]
                        + q1.x * hcol[4] + q1.y * hcol[5] + q1.z * hcol[6] + q1.w * hcol[7]
                        + q2.x * hcol[8] + q2.y * hcol[9] + q2.z * hcol[10] + q2.w * hcol[11];
                o += bias;
                x2v[i] = (o > 0.f) ? o : expm1f(o);
            }
            #pragma unroll
            for (int i = 0; i < NN; ++i) s_h1[g][i][c] = x2v[i];   // column-exclusive
        }
    }
    __syncthreads();

    // ---------------- Phase E: h2 = x2 @ W2 ----------------
    float* s_h2 = s_buf;   // [G][12][64], x tile is dead
    {
        const int d  = t & 63;
        const int tq = t >> 6;            // 0..3 -> rows {tq, tq+4, tq+8}
        float acc2[G][3];
        #pragma unroll
        for (int g = 0; g < G; ++g)
            #pragma unroll
            for (int r = 0; r < 3; ++r) acc2[g][r] = 0.f;

        for (int k0 = 0; k0 < C1; k0 += 8) {
            float w[8];
            #pragma unroll
            for (int kk = 0; kk < 8; ++kk) w[kk] = W2[(k0 + kk) * DD + d];
            #pragma unroll
            for (int g = 0; g < G; ++g) {
                #pragma unroll
                for (int r = 0; r < 3; ++r) {
                    const int n = tq + r * 4;
                    const float* xr = &s_h1[g][n][k0];
                    float4 xa = *reinterpret_cast<const float4*>(xr);
                    float4 xb = *reinterpret_cast<const float4*>(xr + 4);
                    float a = acc2[g][r];
                    a = fmaf(xa.x, w[0], a); a = fmaf(xa.y, w[1], a);
                    a = fmaf(xa.z, w[2], a); a = fmaf(xa.w, w[3], a);
                    a = fmaf(xb.x, w[4], a); a = fmaf(xb.y, w[5], a);
                    a = fmaf(xb.z, w[6], a); a = fmaf(xb.w, w[7], a);
                    acc2[g][r] = a;
                }
            }
        }
        __syncthreads();   // x tile reads long done; ensure everyone past phase D reads of s_buf region (none) — safe ordering before overwrite
        #pragma unroll
        for (int g = 0; g < G; ++g)
            #pragma unroll
            for (int r = 0; r < 3; ++r)
                s_h2[((g * NN) + tq + r * 4) * DD + d] = acc2[g][r];
    }
    __syncthreads();

    // ---------------- Phase F: layer-2 attention logits + softmax ----------------
    if (t < G * NN * 2) {    // 48 tasks
        const int n = t % NN;
        const int sflag = (t / NN) & 1;
        const int g = t / (NN * 2);
        const float* att = sflag ? adst2 : asrc2;
        const float* row = s_h2 + (g * NN + n) * DD;
        float sum = 0.f;
        #pragma unroll
        for (int it = 0; it < 16; ++it) {
            const int dch = ((it + t) & 15) * 4;
            float4 hv = *reinterpret_cast<const float4*>(row + dch);
            float4 av = *reinterpret_cast<const float4*>(att + dch);
            sum += hv.x * av.x + hv.y * av.y + hv.z * av.z + hv.w * av.w;
        }
        if (sflag) s_ed2[g][n] = sum; else s_es2[g][n] = sum;
    }
    __syncthreads();
    if (t < G * NN) {        // 24 tasks
        const int i = t % NN;
        const int g = t / NN;
        const float edv = s_ed2[g][i];
        float l[NN];
        float m = -3.4e38f;
        #pragma unroll
        for (int j = 0; j < NN; ++j) {
            float v = edv + s_es2[g][j];
            v = (v >= 0.f) ? v : NEG * v;
            l[j] = v; m = fmaxf(m, v);
        }
        float s = 0.f;
        #pragma unroll
        for (int j = 0; j < NN; ++j) { float p = expf(l[j] - m); l[j] = p; s += p; }
        const float inv = 1.f / s;
        #pragma unroll
        for (int j = 0; j < NN; ++j) s_alpha2[g][i][j] = l[j] * inv;
    }
    __syncthreads();

    // ---------------- Phase G: out2 = alpha2 @ h2, +b2, elu, mean-pool -----------
    if (t < G * DD) {        // 128 threads
        const int g = t >> 6;
        const int d = t & 63;
        float hcol[NN];
        #pragma unroll
        for (int j = 0; j < NN; ++j) hcol[j] = s_h2[(g * NN + j) * DD + d];
        const float bias = b2[d];
        float gsum = 0.f;
        #pragma unroll
        for (int i = 0; i < NN; ++i) {
            const float4* ar = reinterpret_cast<const float4*>(&s_alpha2[g][i][0]);
            float4 q0 = ar[0], q1 = ar[1], q2 = ar[2];
            float o = q0.x * hcol[0] + q0.y * hcol[1] + q0.z * hcol[2] + q0.w * hcol[3]
                    + q1.x * hcol[4] + q1.y * hcol[5] + q1.z * hcol[6] + q1.w * hcol[7]
                    + q2.x * hcol[8] + q2.y * hcol[9] + q2.z * hcol[10] + q2.w * hcol[11];
            o += bias;
            o = (o > 0.f) ? o : expm1f(o);
            gsum += o;
        }
        s_gmean[g][d] = gsum * (1.f / 12.f);
    }
    __syncthreads();

    // ---------------- Phase H: classifier ----------------
    if (t < G * 32) {
        const int g = t >> 5;
        const int m = t & 31;
        float sum = bc1[m];
        #pragma unroll
        for (int d = 0; d < DD; ++d) sum = fmaf(s_gmean[g][d], Wc1[d * 32 + m], sum);
        s_hc[g][m] = (sum > 0.f) ? sum : 0.f;
    }
    __syncthreads();
    if (t < G) {
        float sum = bc2[0];
        #pragma unroll
        for (int m = 0; m < 32; ++m) sum = fmaf(s_hc[t][m], Wc2[m], sum);
        out[b0 + t] = sum;
    }
}

extern "C" void kernel_launch(void* const* d_in, const int* in_sizes, int n_in,
                              void* d_out, int out_size, void* d_ws, size_t ws_size,
                              hipStream_t stream) {
    const float* x     = (const float*)d_in[0];
    const float* W1    = (const float*)d_in[1];
    const float* asrc1 = (const float*)d_in[2];
    const float* adst1 = (const float*)d_in[3];
    const float* b1    = (const float*)d_in[4];
    const float* W2    = (const float*)d_in[5];
    const float* asrc2 = (const float*)d_in[6];
    const float* adst2 = (const float*)d_in[7];
    const float* b2    = (const float*)d_in[8];
    const float* Wc1   = (const float*)d_in[9];
    const float* bc1   = (const float*)d_in[10];
    const float* Wc2   = (const float*)d_in[11];
    const float* bc2   = (const float*)d_in[12];
    float* outp = (float*)d_out;

    const int B = in_sizes[0] / (NN * FIN);   // 32768
    const int grid = B / G;                   // 16384
    hipLaunchKernelGGL(gat_fused, dim3(grid), dim3(256), 0, stream,
                       x, W1, asrc1, adst1, b1, W2, asrc2, adst2, b2,
                       Wc1, bc1, Wc2, bc2, outp);
}

// Round 3
// 628.838 us; speedup vs baseline: 1.7044x; 1.7044x over previous
//
#include <hip/hip_runtime.h>
#include <math.h>

// Fused ECG-GAT on MI355X: matmuls via split-bf16 MFMA (hi/lo x hi/lo = 4 passes,
// fp32-equivalent accuracy), attention/softmax/classifier in fp32 VALU.
// Kernel 0 pre-transposes W1/W2 into B-fragment-linear hi/lo tables in d_ws.

typedef __attribute__((ext_vector_type(8))) short bf16x8;
typedef __attribute__((ext_vector_type(4))) float f32x4;
typedef unsigned short u16;
typedef unsigned int u32;

constexpr int NN  = 12;
constexpr int FIN = 128;
constexpr int C1  = 256;
constexpr int DD  = 64;
#define NEG 0.2f

// ws layout (ushort elements): W1h[0], W1l[32768], W2h[65536], W2l[81920]
constexpr int WS_W1H = 0, WS_W1L = 32768, WS_W2H = 65536, WS_W2L = 81920;

__device__ __forceinline__ u16 f2bf(float f) {         // RNE float->bf16
    u32 u = __float_as_uint(f);
    u += 0x7fffu + ((u >> 16) & 1u);
    return (u16)(u >> 16);
}
__device__ __forceinline__ float bf2f(u16 h) { return __uint_as_float(((u32)h) << 16); }
__device__ __forceinline__ float bflo(u32 u) { return __uint_as_float(u << 16); }
__device__ __forceinline__ float bfhi(u32 u) { return __uint_as_float(u & 0xffff0000u); }

// ---------------------------------------------------------------------------
// Prep: W1 [128][256] and W2 [256][64] -> bf16 hi/lo, B-fragment-linear:
//   frag idx = ((ntile*KSTEPS + ks)*64 + lane)*8 + j
//   element  = W[k = ks*32 + (lane>>4)*8 + j][col = ntile*16 + (lane&15)]
// ---------------------------------------------------------------------------
__global__ void prep_weights(const float* __restrict__ W1,
                             const float* __restrict__ W2,
                             u16* __restrict__ ws) {
    int idx = blockIdx.x * 256 + threadIdx.x;
    if (idx < 32768) {                       // W1: 16 ntiles x 4 ksteps
        int j = idx & 7, lane = (idx >> 3) & 63, ks = (idx >> 9) & 3, nt = idx >> 11;
        int k = ks * 32 + (lane >> 4) * 8 + j;
        int c = nt * 16 + (lane & 15);
        float v = W1[k * C1 + c];
        u16 hi = f2bf(v);
        ws[WS_W1H + idx] = hi;
        ws[WS_W1L + idx] = f2bf(v - bf2f(hi));
    } else if (idx < 49152) {                // W2: 4 ntiles x 8 ksteps
        int i2 = idx - 32768;
        int j = i2 & 7, lane = (i2 >> 3) & 63, ks = (i2 >> 9) & 7, nt = i2 >> 12;
        int k = ks * 32 + (lane >> 4) * 8 + j;
        int c = nt * 16 + (lane & 15);
        float v = W2[k * DD + c];
        u16 hi = f2bf(v);
        ws[WS_W2H + i2] = hi;
        ws[WS_W2L + i2] = f2bf(v - bf2f(hi));
    }
}

// ---------------------------------------------------------------------------
// Main fused kernel: G=2 graphs / 256-thread block.
// ---------------------------------------------------------------------------
__global__ __launch_bounds__(256, 3) void gat_fused(
    const float* __restrict__ x_in,
    const u16*  __restrict__ wtab,
    const float* __restrict__ asrc1, const float* __restrict__ adst1,
    const float* __restrict__ b1,
    const float* __restrict__ asrc2, const float* __restrict__ adst2,
    const float* __restrict__ b2,
    const float* __restrict__ Wc1,  const float* __restrict__ bc1,
    const float* __restrict__ Wc2,  const float* __restrict__ bc2,
    float* __restrict__ out)
{
    // Union region: phase A input x as bf16 hi/lo [32][136]; then h1/x2 hi/lo [32][264].
    __shared__ __align__(16) unsigned char s_union[34816];
    u16* s_xh  = (u16*)s_union;             // [32][136] (rows 24..31 zeroed)
    u16* s_xl  = s_xh + 32 * 136;
    u16* s_h1h = (u16*)s_union;             // [32][264]
    u16* s_h1l = s_h1h + 32 * 264;
    __shared__ __align__(16) float s_alpha[2][4][NN][NN];
    __shared__ float s_es[2][4][NN], s_ed[2][4][NN];
    __shared__ __align__(16) float s_alpha2[2][NN][NN];
    __shared__ float s_es2[2][NN], s_ed2[2][NN];
    __shared__ __align__(16) float s_h2[24 * DD];
    __shared__ float s_gmean[2][DD];
    __shared__ float s_hc[2][32];

    const int t = threadIdx.x;
    const int lane = t & 63, wave = t >> 6;
    const long b0 = (long)blockIdx.x * 2;

    // ---- stage x: global fp32 -> regs -> bf16 hi/lo in LDS (coalesced) ----
    {
        const float4* src = (const float4*)(x_in + b0 * NN * FIN);
        #pragma unroll
        for (int j = 0; j < 3; ++j) {
            int p = j * 256 + t;                 // float4 index 0..767
            float4 v = src[p];
            int row = p >> 5, col = (p & 31) * 4;
            ushort4 h, l;
            h.x = f2bf(v.x); l.x = f2bf(v.x - bf2f(h.x));
            h.y = f2bf(v.y); l.y = f2bf(v.y - bf2f(h.y));
            h.z = f2bf(v.z); l.z = f2bf(v.z - bf2f(h.z));
            h.w = f2bf(v.w); l.w = f2bf(v.w - bf2f(h.w));
            *(ushort4*)&s_xh[row * 136 + col] = h;
            *(ushort4*)&s_xl[row * 136 + col] = l;
        }
        for (int i = t; i < 544; i += 256) {     // zero pad rows 24..31
            ((u32*)(s_xh + 24 * 136))[i] = 0u;
            ((u32*)(s_xl + 24 * 136))[i] = 0u;
        }
    }
    __syncthreads();

    // ---- Phase A: h1 = x @ W1 via MFMA (M=32 padded, N=256, K=128) ----
    {
        const int arow = lane & 15, aks = lane >> 4;
        bf16x8 ah[2][4], al[2][4];
        #pragma unroll
        for (int m = 0; m < 2; ++m)
            #pragma unroll
            for (int ks = 0; ks < 4; ++ks) {
                int off = (m * 16 + arow) * 136 + ks * 32 + aks * 8;
                ah[m][ks] = *(const bf16x8*)&s_xh[off];
                al[m][ks] = *(const bf16x8*)&s_xl[off];
            }
        __syncthreads();   // all x reads done -> h1 may overlay

        #pragma unroll
        for (int nti = 0; nti < 4; ++nti) {
            const int nt = wave * 4 + nti;       // wave w owns cols 64w..64w+63 (= head w)
            bf16x8 bh[4], bl[4];
            #pragma unroll
            for (int ks = 0; ks < 4; ++ks) {
                int off = ((nt * 4 + ks) * 64 + lane) * 8;
                bh[ks] = *(const bf16x8*)&wtab[WS_W1H + off];
                bl[ks] = *(const bf16x8*)&wtab[WS_W1L + off];
            }
            f32x4 acc[2] = { {0.f,0.f,0.f,0.f}, {0.f,0.f,0.f,0.f} };
            #pragma unroll
            for (int ks = 0; ks < 4; ++ks)
                #pragma unroll
                for (int m = 0; m < 2; ++m) {
                    acc[m] = __builtin_amdgcn_mfma_f32_16x16x32_bf16(ah[m][ks], bh[ks], acc[m], 0, 0, 0);
                    acc[m] = __builtin_amdgcn_mfma_f32_16x16x32_bf16(ah[m][ks], bl[ks], acc[m], 0, 0, 0);
                    acc[m] = __builtin_amdgcn_mfma_f32_16x16x32_bf16(al[m][ks], bh[ks], acc[m], 0, 0, 0);
                    acc[m] = __builtin_amdgcn_mfma_f32_16x16x32_bf16(al[m][ks], bl[ks], acc[m], 0, 0, 0);
                }
            const int ccol = nt * 16 + (lane & 15);
            #pragma unroll
            for (int m = 0; m < 2; ++m)
                #pragma unroll
                for (int r = 0; r < 4; ++r) {
                    int row = m * 16 + (lane >> 4) * 4 + r;   // C: col=lane&15, row=(lane>>4)*4+r
                    float v = acc[m][r];
                    u16 hi = f2bf(v);
                    s_h1h[row * 264 + ccol] = hi;
                    s_h1l[row * 264 + ccol] = f2bf(v - bf2f(hi));
                }
        }
    }
    __syncthreads();

    // ---- Phase B: es/ed logits (192 tasks) ----
    if (t < 192) {
        int tmp = t;
        const int n = tmp % NN; tmp /= NN;
        const int h = tmp & 3; tmp >>= 2;
        const int sflag = tmp & 1;
        const int g = tmp >> 1;
        const float* att = (sflag ? adst1 : asrc1) + h * DD;
        const int base = (g * NN + n) * 264 + h * DD;
        float sum = 0.f;
        #pragma unroll
        for (int it = 0; it < 8; ++it) {
            const int ch = ((it + t) & 7) * 8;   // rotated chunks
            uint4 uh = *(const uint4*)&s_h1h[base + ch];
            uint4 ul = *(const uint4*)&s_h1l[base + ch];
            float4 a0 = *(const float4*)&att[ch];
            float4 a1 = *(const float4*)&att[ch + 4];
            sum += (bflo(uh.x) + bflo(ul.x)) * a0.x;
            sum += (bfhi(uh.x) + bfhi(ul.x)) * a0.y;
            sum += (bflo(uh.y) + bflo(ul.y)) * a0.z;
            sum += (bfhi(uh.y) + bfhi(ul.y)) * a0.w;
            sum += (bflo(uh.z) + bflo(ul.z)) * a1.x;
            sum += (bfhi(uh.z) + bfhi(ul.z)) * a1.y;
            sum += (bflo(uh.w) + bflo(ul.w)) * a1.z;
            sum += (bfhi(uh.w) + bfhi(ul.w)) * a1.w;
        }
        if (sflag) s_ed[g][h][n] = sum; else s_es[g][h][n] = sum;
    }
    __syncthreads();

    // ---- Phase C: softmax over sources (96 tasks) ----
    if (t < 96) {
        const int i = t % NN;
        const int h = (t / NN) & 3;
        const int g = t / (NN * 4);
        const float edv = s_ed[g][h][i];
        float l[NN];
        float m = -3.4e38f;
        #pragma unroll
        for (int j = 0; j < NN; ++j) {
            float v = edv + s_es[g][h][j];
            v = (v >= 0.f) ? v : NEG * v;
            l[j] = v; m = fmaxf(m, v);
        }
        float s = 0.f;
        #pragma unroll
        for (int j = 0; j < NN; ++j) { float p = __expf(l[j] - m); l[j] = p; s += p; }
        const float inv = 1.f / s;
        #pragma unroll
        for (int j = 0; j < NN; ++j) s_alpha[g][h][i][j] = l[j] * inv;
    }
    __syncthreads();

    // ---- Phase D: x2 = elu(alpha @ h1 + b1), in place (column-exclusive) ----
    {
        const int c = t;
        const int hh = c >> 6;
        const float bias = b1[c];
        #pragma unroll
        for (int g = 0; g < 2; ++g) {
            float hcol[NN];
            #pragma unroll
            for (int j = 0; j < NN; ++j) {
                int off = (g * NN + j) * 264 + c;
                hcol[j] = bf2f(s_h1h[off]) + bf2f(s_h1l[off]);
            }
            float x2v[NN];
            #pragma unroll
            for (int i = 0; i < NN; ++i) {
                const float4* ar = (const float4*)&s_alpha[g][hh][i][0];
                float4 q0 = ar[0], q1 = ar[1], q2 = ar[2];
                float o = q0.x*hcol[0] + q0.y*hcol[1] + q0.z*hcol[2] + q0.w*hcol[3]
                        + q1.x*hcol[4] + q1.y*hcol[5] + q1.z*hcol[6] + q1.w*hcol[7]
                        + q2.x*hcol[8] + q2.y*hcol[9] + q2.z*hcol[10] + q2.w*hcol[11];
                o += bias;
                x2v[i] = (o > 0.f) ? o : (__expf(o) - 1.f);
            }
            #pragma unroll
            for (int i = 0; i < NN; ++i) {
                int off = (g * NN + i) * 264 + c;
                u16 hi = f2bf(x2v[i]);
                s_h1h[off] = hi;
                s_h1l[off] = f2bf(x2v[i] - bf2f(hi));
            }
        }
    }
    __syncthreads();

    // ---- Phase E: h2 = x2 @ W2 via MFMA (M=32 padded, N=64, K=256) ----
    {
        const int arow = lane & 15, aks = lane >> 4;
        f32x4 acc[2] = { {0.f,0.f,0.f,0.f}, {0.f,0.f,0.f,0.f} };
        #pragma unroll
        for (int ks = 0; ks < 8; ++ks) {
            int woff = ((wave * 8 + ks) * 64 + lane) * 8;
            bf16x8 bh = *(const bf16x8*)&wtab[WS_W2H + woff];
            bf16x8 bl = *(const bf16x8*)&wtab[WS_W2L + woff];
            #pragma unroll
            for (int m = 0; m < 2; ++m) {
                int off = (m * 16 + arow) * 264 + ks * 32 + aks * 8;
                bf16x8 ah = *(const bf16x8*)&s_h1h[off];
                bf16x8 al = *(const bf16x8*)&s_h1l[off];
                acc[m] = __builtin_amdgcn_mfma_f32_16x16x32_bf16(ah, bh, acc[m], 0, 0, 0);
                acc[m] = __builtin_amdgcn_mfma_f32_16x16x32_bf16(ah, bl, acc[m], 0, 0, 0);
                acc[m] = __builtin_amdgcn_mfma_f32_16x16x32_bf16(al, bh, acc[m], 0, 0, 0);
                acc[m] = __builtin_amdgcn_mfma_f32_16x16x32_bf16(al, bl, acc[m], 0, 0, 0);
            }
        }
        const int ccol = wave * 16 + (lane & 15);
        #pragma unroll
        for (int m = 0; m < 2; ++m)
            #pragma unroll
            for (int r = 0; r < 4; ++r) {
                int row = m * 16 + (lane >> 4) * 4 + r;
                if (row < 24) s_h2[row * DD + ccol] = acc[m][r];
            }
    }
    __syncthreads();

    // ---- Phase F: layer-2 logits + softmax ----
    if (t < 48) {
        const int n = t % NN;
        const int sflag = (t / NN) & 1;
        const int g = t / (NN * 2);
        const float* att = sflag ? adst2 : asrc2;
        const float* row = s_h2 + (g * NN + n) * DD;
        float sum = 0.f;
        #pragma unroll
        for (int it = 0; it < 16; ++it) {
            const int dch = ((it + t) & 15) * 4;
            float4 hv = *(const float4*)&row[dch];
            float4 av = *(const float4*)&att[dch];
            sum += hv.x * av.x + hv.y * av.y + hv.z * av.z + hv.w * av.w;
        }
        if (sflag) s_ed2[g][n] = sum; else s_es2[g][n] = sum;
    }
    __syncthreads();
    if (t < 24) {
        const int i = t % NN;
        const int g = t / NN;
        const float edv = s_ed2[g][i];
        float l[NN];
        float m = -3.4e38f;
        #pragma unroll
        for (int j = 0; j < NN; ++j) {
            float v = edv + s_es2[g][j];
            v = (v >= 0.f) ? v : NEG * v;
            l[j] = v; m = fmaxf(m, v);
        }
        float s = 0.f;
        #pragma unroll
        for (int j = 0; j < NN; ++j) { float p = __expf(l[j] - m); l[j] = p; s += p; }
        const float inv = 1.f / s;
        #pragma unroll
        for (int j = 0; j < NN; ++j) s_alpha2[g][i][j] = l[j] * inv;
    }
    __syncthreads();

    // ---- Phase G: out2 = elu(alpha2 @ h2 + b2), mean-pool ----
    if (t < 128) {
        const int g = t >> 6;
        const int d = t & 63;
        float hcol[NN];
        #pragma unroll
        for (int j = 0; j < NN; ++j) hcol[j] = s_h2[(g * NN + j) * DD + d];
        const float bias = b2[d];
        float gsum = 0.f;
        #pragma unroll
        for (int i = 0; i < NN; ++i) {
            const float4* ar = (const float4*)&s_alpha2[g][i][0];
            float4 q0 = ar[0], q1 = ar[1], q2 = ar[2];
            float o = q0.x*hcol[0] + q0.y*hcol[1] + q0.z*hcol[2] + q0.w*hcol[3]
                    + q1.x*hcol[4] + q1.y*hcol[5] + q1.z*hcol[6] + q1.w*hcol[7]
                    + q2.x*hcol[8] + q2.y*hcol[9] + q2.z*hcol[10] + q2.w*hcol[11];
            o += bias;
            o = (o > 0.f) ? o : (__expf(o) - 1.f);
            gsum += o;
        }
        s_gmean[g][d] = gsum * (1.f / 12.f);
    }
    __syncthreads();

    // ---- Phase H: classifier ----
    if (t < 64) {
        const int g = t >> 5;
        const int m = t & 31;
        float sum = bc1[m];
        #pragma unroll
        for (int d = 0; d < DD; ++d) sum = fmaf(s_gmean[g][d], Wc1[d * 32 + m], sum);
        s_hc[g][m] = (sum > 0.f) ? sum : 0.f;
    }
    __syncthreads();
    if (t < 2) {
        float sum = bc2[0];
        #pragma unroll
        for (int m = 0; m < 32; ++m) sum = fmaf(s_hc[t][m], Wc2[m], sum);
        out[b0 + t] = sum;
    }
}

extern "C" void kernel_launch(void* const* d_in, const int* in_sizes, int n_in,
                              void* d_out, int out_size, void* d_ws, size_t ws_size,
                              hipStream_t stream) {
    const float* x     = (const float*)d_in[0];
    const float* W1    = (const float*)d_in[1];
    const float* asrc1 = (const float*)d_in[2];
    const float* adst1 = (const float*)d_in[3];
    const float* b1    = (const float*)d_in[4];
    const float* W2    = (const float*)d_in[5];
    const float* asrc2 = (const float*)d_in[6];
    const float* adst2 = (const float*)d_in[7];
    const float* b2    = (const float*)d_in[8];
    const float* Wc1   = (const float*)d_in[9];
    const float* bc1   = (const float*)d_in[10];
    const float* Wc2   = (const float*)d_in[11];
    const float* bc2   = (const float*)d_in[12];
    float* outp = (float*)d_out;

    const int B = in_sizes[0] / (NN * FIN);   // 32768
    u16* wtab = (u16*)d_ws;                   // needs 196608 B of ws

    hipLaunchKernelGGL(prep_weights, dim3(192), dim3(256), 0, stream, W1, W2, wtab);
    hipLaunchKernelGGL(gat_fused, dim3(B / 2), dim3(256), 0, stream,
                       x, wtab, asrc1, adst1, b1, asrc2, adst2, b2,
                       Wc1, bc1, Wc2, bc2, outp);
}

// Round 6
// 559.666 us; speedup vs baseline: 1.9150x; 1.1236x over previous
//
#include <hip/hip_runtime.h>
#include <math.h>

// Fused ECG-GAT on MI355X, R4:
//  - matmuls via split-bf16 MFMA (hi/lo, 3 passes: ah*bh + ah*bl + al*bh)
//  - h1 kept fp32 in LDS for attention phases (no hi/lo round-trip)
//  - x and x2 staged in XOR-swizzled A-fragment-linear bf16 hi/lo layout
//    (u16 addr = (u ^ ((u>>4)&7))*8 + j, u = (ks*2+m)*64 + aks*16 + r15)
// Kernel 0 pre-transposes W1/W2 into B-fragment-linear hi/lo tables in d_ws.

typedef __attribute__((ext_vector_type(8))) short bf16x8;
typedef __attribute__((ext_vector_type(4))) float f32x4;
typedef unsigned short u16;
typedef unsigned int u32;

constexpr int NN  = 12;
constexpr int FIN = 128;
constexpr int C1  = 256;
constexpr int DD  = 64;
#define NEG 0.2f

// ws layout (ushort elements): W1h[0], W1l[32768], W2h[65536], W2l[81920]
constexpr int WS_W1H = 0, WS_W1L = 32768, WS_W2H = 65536, WS_W2L = 81920;

__device__ __forceinline__ u16 f2bf(float f) {         // RNE float->bf16
    u32 u = __float_as_uint(f);
    u += 0x7fffu + ((u >> 16) & 1u);
    return (u16)(u >> 16);
}
__device__ __forceinline__ float bf2f(u16 h) { return __uint_as_float(((u32)h) << 16); }
__device__ __forceinline__ int swz(int u) { return u ^ ((u >> 4) & 7); }  // 16B-unit swizzle

// ---------------------------------------------------------------------------
__global__ void prep_weights(const float* __restrict__ W1,
                             const float* __restrict__ W2,
                             u16* __restrict__ ws) {
    int idx = blockIdx.x * 256 + threadIdx.x;
    if (idx < 32768) {                       // W1: 16 ntiles x 4 ksteps
        int j = idx & 7, lane = (idx >> 3) & 63, ks = (idx >> 9) & 3, nt = idx >> 11;
        int k = ks * 32 + (lane >> 4) * 8 + j;
        int c = nt * 16 + (lane & 15);
        float v = W1[k * C1 + c];
        u16 hi = f2bf(v);
        ws[WS_W1H + idx] = hi;
        ws[WS_W1L + idx] = f2bf(v - bf2f(hi));
    } else if (idx < 49152) {                // W2: 4 ntiles x 8 ksteps
        int i2 = idx - 32768;
        int j = i2 & 7, lane = (i2 >> 3) & 63, ks = (i2 >> 9) & 7, nt = i2 >> 12;
        int k = ks * 32 + (lane >> 4) * 8 + j;
        int c = nt * 16 + (lane & 15);
        float v = W2[k * DD + c];
        u16 hi = f2bf(v);
        ws[WS_W2H + i2] = hi;
        ws[WS_W2L + i2] = f2bf(v - bf2f(hi));
    }
}

// ---------------------------------------------------------------------------
__global__ __launch_bounds__(256, 3) void gat_fused(
    const float* __restrict__ x_in,
    const u16*  __restrict__ wtab,
    const float* __restrict__ asrc1, const float* __restrict__ adst1,
    const float* __restrict__ b1,
    const float* __restrict__ asrc2, const float* __restrict__ adst2,
    const float* __restrict__ b2,
    const float* __restrict__ Wc1,  const float* __restrict__ bc1,
    const float* __restrict__ Wc2,  const float* __restrict__ bc2,
    float* __restrict__ out)
{
    // Union region (32 KB):
    //   stage/A : x frags  hi @0 (8KB), lo @8192 (8KB)
    //   A..D    : h1 fp32 [24][268] @0 (25728 B)
    //   D..E    : x2 frags hi @0 (16KB), lo @16384 (16KB)
    __shared__ __align__(16) unsigned char s_union[32768];
    u16*   s_xfh  = (u16*)s_union;
    u16*   s_xfl  = (u16*)(s_union + 8192);
    float* s_h1f  = (float*)s_union;           // stride 268
    u16*   s_x2h  = (u16*)s_union;
    u16*   s_x2l  = (u16*)(s_union + 16384);
    __shared__ __align__(16) float s_alpha[2][4][NN][NN];
    __shared__ float s_es[2][4][NN], s_ed[2][4][NN];
    __shared__ __align__(16) float s_alpha2[2][NN][NN];
    __shared__ float s_es2[2][NN], s_ed2[2][NN];
    __shared__ __align__(16) float s_h2[24 * 68];   // stride 68
    __shared__ float s_gmean[2][DD];
    __shared__ float s_hc[2][32];

    const int t = threadIdx.x;
    const int lane = t & 63, wave = t >> 6;
    const long b0 = (long)blockIdx.x * 2;

    // ---- stage x: fp32 -> bf16 hi/lo, swizzled A-fragment layout ----
    {
        const float4* src = (const float4*)(x_in + b0 * NN * FIN);
        #pragma unroll
        for (int j = 0; j < 3; ++j) {
            int p = j * 256 + t;                 // float4 index 0..767
            float4 v = src[p];
            int row = p >> 5, cb = (p & 31) * 4;
            int m = row >> 4, r15 = row & 15;
            int ks = cb >> 5, aks = (cb >> 3) & 3, jj = cb & 7;
            int us = swz((ks * 2 + m) * 64 + aks * 16 + r15);
            ushort4 h, l;
            h.x = f2bf(v.x); l.x = f2bf(v.x - bf2f(h.x));
            h.y = f2bf(v.y); l.y = f2bf(v.y - bf2f(h.y));
            h.z = f2bf(v.z); l.z = f2bf(v.z - bf2f(h.z));
            h.w = f2bf(v.w); l.w = f2bf(v.w - bf2f(h.w));
            *(ushort4*)&s_xfh[us * 8 + jj] = h;
            *(ushort4*)&s_xfl[us * 8 + jj] = l;
        }
        if (t < 128) {                           // zero pad rows 24..31 (m=1, r15 8..15)
            int ks = t >> 5, aks = (t >> 3) & 3, r15 = 8 + (t & 7);
            int us = swz((ks * 2 + 1) * 64 + aks * 16 + r15);
            *(uint4*)&s_xfh[us * 8] = make_uint4(0, 0, 0, 0);
            *(uint4*)&s_xfl[us * 8] = make_uint4(0, 0, 0, 0);
        }
    }
    __syncthreads();

    // ---- Phase A: h1 = x @ W1 via MFMA (M=32 padded, N=256, K=128) ----
    {
        bf16x8 ah[2][4], al[2][4];
        #pragma unroll
        for (int m = 0; m < 2; ++m)
            #pragma unroll
            for (int ks = 0; ks < 4; ++ks) {
                int us = swz((ks * 2 + m) * 64 + lane);
                ah[m][ks] = *(const bf16x8*)&s_xfh[us * 8];
                al[m][ks] = *(const bf16x8*)&s_xfl[us * 8];
            }
        __syncthreads();   // x reads done -> h1f may overlay

        #pragma unroll
        for (int nti = 0; nti < 4; ++nti) {
            const int nt = wave * 4 + nti;
            bf16x8 bh[4], bl[4];
            #pragma unroll
            for (int ks = 0; ks < 4; ++ks) {
                int off = ((nt * 4 + ks) * 64 + lane) * 8;
                bh[ks] = *(const bf16x8*)&wtab[WS_W1H + off];
                bl[ks] = *(const bf16x8*)&wtab[WS_W1L + off];
            }
            f32x4 acc[2] = { {0.f,0.f,0.f,0.f}, {0.f,0.f,0.f,0.f} };
            #pragma unroll
            for (int ks = 0; ks < 4; ++ks)
                #pragma unroll
                for (int m = 0; m < 2; ++m) {
                    acc[m] = __builtin_amdgcn_mfma_f32_16x16x32_bf16(ah[m][ks], bh[ks], acc[m], 0, 0, 0);
                    acc[m] = __builtin_amdgcn_mfma_f32_16x16x32_bf16(ah[m][ks], bl[ks], acc[m], 0, 0, 0);
                    acc[m] = __builtin_amdgcn_mfma_f32_16x16x32_bf16(al[m][ks], bh[ks], acc[m], 0, 0, 0);
                }
            const int ccol = nt * 16 + (lane & 15);
            #pragma unroll
            for (int m = 0; m < 2; ++m)
                #pragma unroll
                for (int r = 0; r < 4; ++r) {
                    int row = m * 16 + (lane >> 4) * 4 + r;
                    if (row < 24) s_h1f[row * 268 + ccol] = acc[m][r];
                }
        }
    }
    __syncthreads();

    // ---- Phase B: es/ed logits (192 tasks), fp32 reads ----
    if (t < 192) {
        int tmp = t;
        const int n = tmp % NN; tmp /= NN;
        const int h = tmp & 3; tmp >>= 2;
        const int sflag = tmp & 1;
        const int g = tmp >> 1;
        const float* att = (sflag ? adst1 : asrc1) + h * DD;
        const float* row = s_h1f + (g * NN + n) * 268 + h * DD;
        float sum = 0.f;
        #pragma unroll
        for (int it = 0; it < 8; ++it) {
            const int ch = ((it + t) & 7) * 8;   // rotated chunks
            float4 h0 = *(const float4*)&row[ch];
            float4 h1v = *(const float4*)&row[ch + 4];
            float4 a0 = *(const float4*)&att[ch];
            float4 a1 = *(const float4*)&att[ch + 4];
            sum += h0.x*a0.x + h0.y*a0.y + h0.z*a0.z + h0.w*a0.w
                 + h1v.x*a1.x + h1v.y*a1.y + h1v.z*a1.z + h1v.w*a1.w;
        }
        if (sflag) s_ed[g][h][n] = sum; else s_es[g][h][n] = sum;
    }
    __syncthreads();

    // ---- Phase C: softmax over sources (96 tasks) ----
    if (t < 96) {
        const int i = t % NN;
        const int h = (t / NN) & 3;
        const int g = t / (NN * 4);
        const float edv = s_ed[g][h][i];
        float l[NN];
        float m = -3.4e38f;
        #pragma unroll
        for (int j = 0; j < NN; ++j) {
            float v = edv + s_es[g][h][j];
            v = (v >= 0.f) ? v : NEG * v;
            l[j] = v; m = fmaxf(m, v);
        }
        float s = 0.f;
        #pragma unroll
        for (int j = 0; j < NN; ++j) { float p = __expf(l[j] - m); l[j] = p; s += p; }
        const float inv = 1.f / s;
        #pragma unroll
        for (int j = 0; j < NN; ++j) s_alpha[g][h][i][j] = l[j] * inv;
    }
    __syncthreads();

    // ---- Phase D: x2 = elu(alpha @ h1 + b1) -> regs -> swizzled bf16 frags ----
    {
        const int c = t;
        const int hh = c >> 6;
        const float bias = b1[c];
        float x2v[2][NN];
        #pragma unroll
        for (int g = 0; g < 2; ++g) {
            float hcol[NN];
            #pragma unroll
            for (int j = 0; j < NN; ++j) hcol[j] = s_h1f[(g * NN + j) * 268 + c];
            #pragma unroll
            for (int i = 0; i < NN; ++i) {
                const float4* ar = (const float4*)&s_alpha[g][hh][i][0];
                float4 q0 = ar[0], q1 = ar[1], q2 = ar[2];
                float o = q0.x*hcol[0] + q0.y*hcol[1] + q0.z*hcol[2] + q0.w*hcol[3]
                        + q1.x*hcol[4] + q1.y*hcol[5] + q1.z*hcol[6] + q1.w*hcol[7]
                        + q2.x*hcol[8] + q2.y*hcol[9] + q2.z*hcol[10] + q2.w*hcol[11];
                o += bias;
                x2v[g][i] = (o > 0.f) ? o : (__expf(o) - 1.f);
            }
        }
        __syncthreads();   // all h1f reads done -> x2 frags may overlay

        const int ks_c = c >> 5, aks_c = (c >> 3) & 3, j_c = c & 7;
        #pragma unroll
        for (int g = 0; g < 2; ++g)
            #pragma unroll
            for (int i = 0; i < NN; ++i) {
                int row = g * NN + i;
                int us = swz((ks_c * 2 + (row >> 4)) * 64 + aks_c * 16 + (row & 15));
                float v = x2v[g][i];
                u16 hi = f2bf(v);
                s_x2h[us * 8 + j_c] = hi;
                s_x2l[us * 8 + j_c] = f2bf(v - bf2f(hi));
            }
        {   // zero pad rows 24..31: 256 units (ks 0..7, aks 0..3, r15 8..15)
            int ks = t >> 5, aks = (t >> 3) & 3, r15 = 8 + (t & 7);
            int us = swz((ks * 2 + 1) * 64 + aks * 16 + r15);
            *(uint4*)&s_x2h[us * 8] = make_uint4(0, 0, 0, 0);
            *(uint4*)&s_x2l[us * 8] = make_uint4(0, 0, 0, 0);
        }
    }
    __syncthreads();

    // ---- Phase E: h2 = x2 @ W2 via MFMA (M=32 padded, N=64, K=256) ----
    {
        f32x4 acc[2] = { {0.f,0.f,0.f,0.f}, {0.f,0.f,0.f,0.f} };
        #pragma unroll
        for (int ks = 0; ks < 8; ++ks) {
            int woff = ((wave * 8 + ks) * 64 + lane) * 8;
            bf16x8 bh = *(const bf16x8*)&wtab[WS_W2H + woff];
            bf16x8 bl = *(const bf16x8*)&wtab[WS_W2L + woff];
            #pragma unroll
            for (int m = 0; m < 2; ++m) {
                int us = swz((ks * 2 + m) * 64 + lane);
                bf16x8 ah = *(const bf16x8*)&s_x2h[us * 8];
                bf16x8 al = *(const bf16x8*)&s_x2l[us * 8];
                acc[m] = __builtin_amdgcn_mfma_f32_16x16x32_bf16(ah, bh, acc[m], 0, 0, 0);
                acc[m] = __builtin_amdgcn_mfma_f32_16x16x32_bf16(ah, bl, acc[m], 0, 0, 0);
                acc[m] = __builtin_amdgcn_mfma_f32_16x16x32_bf16(al, bh, acc[m], 0, 0, 0);
            }
        }
        const int ccol = wave * 16 + (lane & 15);
        #pragma unroll
        for (int m = 0; m < 2; ++m)
            #pragma unroll
            for (int r = 0; r < 4; ++r) {
                int row = m * 16 + (lane >> 4) * 4 + r;
                if (row < 24) s_h2[row * 68 + ccol] = acc[m][r];
            }
    }
    __syncthreads();

    // ---- Phase F: layer-2 logits + softmax ----
    if (t < 48) {
        const int n = t % NN;
        const int sflag = (t / NN) & 1;
        const int g = t / (NN * 2);
        const float* att = sflag ? adst2 : asrc2;
        const float* row = s_h2 + (g * NN + n) * 68;
        float sum = 0.f;
        #pragma unroll
        for (int it = 0; it < 16; ++it) {
            const int dch = ((it + t) & 15) * 4;
            float4 hv = *(const float4*)&row[dch];
            float4 av = *(const float4*)&att[dch];
            sum += hv.x * av.x + hv.y * av.y + hv.z * av.z + hv.w * av.w;
        }
        if (sflag) s_ed2[g][n] = sum; else s_es2[g][n] = sum;
    }
    __syncthreads();
    if (t < 24) {
        const int i = t % NN;
        const int g = t / NN;
        const float edv = s_ed2[g][i];
        float l[NN];
        float m = -3.4e38f;
        #pragma unroll
        for (int j = 0; j < NN; ++j) {
            float v = edv + s_es2[g][j];
            v = (v >= 0.f) ? v : NEG * v;
            l[j] = v; m = fmaxf(m, v);
        }
        float s = 0.f;
        #pragma unroll
        for (int j = 0; j < NN; ++j) { float p = __expf(l[j] - m); l[j] = p; s += p; }
        const float inv = 1.f / s;
        #pragma unroll
        for (int j = 0; j < NN; ++j) s_alpha2[g][i][j] = l[j] * inv;
    }
    __syncthreads();

    // ---- Phase G: out2 = elu(alpha2 @ h2 + b2), mean-pool ----
    if (t < 128) {
        const int g = t >> 6;
        const int d = t & 63;
        float hcol[NN];
        #pragma unroll
        for (int j = 0; j < NN; ++j) hcol[j] = s_h2[(g * NN + j) * 68 + d];
        const float bias = b2[d];
        float gsum = 0.f;
        #pragma unroll
        for (int i = 0; i < NN; ++i) {
            const float4* ar = (const float4*)&s_alpha2[g][i][0];
            float4 q0 = ar[0], q1 = ar[1], q2 = ar[2];
            float o = q0.x*hcol[0] + q0.y*hcol[1] + q0.z*hcol[2] + q0.w*hcol[3]
                    + q1.x*hcol[4] + q1.y*hcol[5] + q1.z*hcol[6] + q1.w*hcol[7]
                    + q2.x*hcol[8] + q2.y*hcol[9] + q2.z*hcol[10] + q2.w*hcol[11];
            o += bias;
            o = (o > 0.f) ? o : (__expf(o) - 1.f);
            gsum += o;
        }
        s_gmean[g][d] = gsum * (1.f / 12.f);
    }
    __syncthreads();

    // ---- Phase H: classifier ----
    if (t < 64) {
        const int g = t >> 5;
        const int m = t & 31;
        float sum = bc1[m];
        #pragma unroll
        for (int d = 0; d < DD; ++d) sum = fmaf(s_gmean[g][d], Wc1[d * 32 + m], sum);
        s_hc[g][m] = (sum > 0.f) ? sum : 0.f;
    }
    __syncthreads();
    if (t < 2) {
        float sum = bc2[0];
        #pragma unroll
        for (int m = 0; m < 32; ++m) sum = fmaf(s_hc[t][m], Wc2[m], sum);
        out[b0 + t] = sum;
    }
}

extern "C" void kernel_launch(void* const* d_in, const int* in_sizes, int n_in,
                              void* d_out, int out_size, void* d_ws, size_t ws_size,
                              hipStream_t stream) {
    const float* x     = (const float*)d_in[0];
    const float* W1    = (const float*)d_in[1];
    const float* asrc1 = (const float*)d_in[2];
    const float* adst1 = (const float*)d_in[3];
    const float* b1    = (const float*)d_in[4];
    const float* W2    = (const float*)d_in[5];
    const float* asrc2 = (const float*)d_in[6];
    const float* adst2 = (const float*)d_in[7];
    const float* b2    = (const float*)d_in[8];
    const float* Wc1   = (const float*)d_in[9];
    const float* bc1   = (const float*)d_in[10];
    const float* Wc2   = (const float*)d_in[11];
    const float* bc2   = (const float*)d_in[12];
    float* outp = (float*)d_out;

    const int B = in_sizes[0] / (NN * FIN);   // 32768
    u16* wtab = (u16*)d_ws;                   // needs 196608 B of ws

    hipLaunchKernelGGL(prep_weights, dim3(192), dim3(256), 0, stream, W1, W2, wtab);
    hipLaunchKernelGGL(gat_fused, dim3(B / 2), dim3(256), 0, stream,
                       x, wtab, asrc1, adst1, b1, asrc2, adst2, b2,
                       Wc1, bc1, Wc2, bc2, outp);
}

// Round 7
// 525.599 us; speedup vs baseline: 2.0391x; 1.0648x over previous
//
#include <hip/hip_runtime.h>
#include <math.h>

// Fused ECG-GAT on MI355X, R7:
//  - R4 structure (split-bf16 MFMA 3-pass, fp32 h1, XOR-swizzled frag staging)
//  - LDS overlay: h2/alpha2/es2/ed2/gmean/hc carved from the big union after
//    the x2 fragments die -> 38144 B total -> 4 blocks/CU (was 3)
//  - pad-row zeroing removed (MFMA A-operand garbage rows only affect
//    discarded C rows 24..31; each C row depends only on its own A row)

typedef __attribute__((ext_vector_type(8))) short bf16x8;
typedef __attribute__((ext_vector_type(4))) float f32x4;
typedef unsigned short u16;
typedef unsigned int u32;

constexpr int NN  = 12;
constexpr int FIN = 128;
constexpr int C1  = 256;
constexpr int DD  = 64;
#define NEG 0.2f

// ws layout (ushort elements): W1h[0], W1l[32768], W2h[65536], W2l[81920]
constexpr int WS_W1H = 0, WS_W1L = 32768, WS_W2H = 65536, WS_W2L = 81920;

__device__ __forceinline__ u16 f2bf(float f) {         // RNE float->bf16
    u32 u = __float_as_uint(f);
    u += 0x7fffu + ((u >> 16) & 1u);
    return (u16)(u >> 16);
}
__device__ __forceinline__ float bf2f(u16 h) { return __uint_as_float(((u32)h) << 16); }
__device__ __forceinline__ int swz(int u) { return u ^ ((u >> 4) & 7); }  // 16B-unit swizzle

// ---------------------------------------------------------------------------
__global__ void prep_weights(const float* __restrict__ W1,
                             const float* __restrict__ W2,
                             u16* __restrict__ ws) {
    int idx = blockIdx.x * 256 + threadIdx.x;
    if (idx < 32768) {                       // W1: 16 ntiles x 4 ksteps
        int j = idx & 7, lane = (idx >> 3) & 63, ks = (idx >> 9) & 3, nt = idx >> 11;
        int k = ks * 32 + (lane >> 4) * 8 + j;
        int c = nt * 16 + (lane & 15);
        float v = W1[k * C1 + c];
        u16 hi = f2bf(v);
        ws[WS_W1H + idx] = hi;
        ws[WS_W1L + idx] = f2bf(v - bf2f(hi));
    } else if (idx < 49152) {                // W2: 4 ntiles x 8 ksteps
        int i2 = idx - 32768;
        int j = i2 & 7, lane = (i2 >> 3) & 63, ks = (i2 >> 9) & 7, nt = i2 >> 12;
        int k = ks * 32 + (lane >> 4) * 8 + j;
        int c = nt * 16 + (lane & 15);
        float v = W2[k * DD + c];
        u16 hi = f2bf(v);
        ws[WS_W2H + i2] = hi;
        ws[WS_W2L + i2] = f2bf(v - bf2f(hi));
    }
}

// ---------------------------------------------------------------------------
__global__ __launch_bounds__(256, 4) void gat_fused(
    const float* __restrict__ x_in,
    const u16*  __restrict__ wtab,
    const float* __restrict__ asrc1, const float* __restrict__ adst1,
    const float* __restrict__ b1,
    const float* __restrict__ asrc2, const float* __restrict__ adst2,
    const float* __restrict__ b2,
    const float* __restrict__ Wc1,  const float* __restrict__ bc1,
    const float* __restrict__ Wc2,  const float* __restrict__ bc2,
    float* __restrict__ out)
{
    // Union region (32 KB), timeline:
    //   stage..A : x frags  hi @0 (8KB), lo @8192 (8KB)
    //   A..D     : h1 fp32 [24][268] @0 (25728 B)
    //   D..E     : x2 frags hi @0 (16KB), lo @16384 (16KB)
    //   E..end   : h2 fp32 [24][68] @0 (6528 B); alpha2/es2/ed2/gmean/hc @8192
    __shared__ __align__(16) unsigned char s_union[32768];
    u16*   s_xfh  = (u16*)s_union;
    u16*   s_xfl  = (u16*)(s_union + 8192);
    float* s_h1f  = (float*)s_union;           // stride 268
    u16*   s_x2h  = (u16*)s_union;
    u16*   s_x2l  = (u16*)(s_union + 16384);
    float* s_h2   = (float*)s_union;           // stride 68
    float* s_al2  = (float*)(s_union + 8192);          // [2][12][12]
    float* s_es2  = (float*)(s_union + 8192 + 1152);   // [2][12]
    float* s_ed2  = (float*)(s_union + 8192 + 1248);   // [2][12]
    float* s_gm   = (float*)(s_union + 8192 + 1344);   // [2][64]
    float* s_hc   = (float*)(s_union + 8192 + 1856);   // [2][32]
    // alive B..D, coexists with h1f -> separate:
    __shared__ __align__(16) float s_alpha[2][4][NN][NN];
    __shared__ float s_es[2][4][NN], s_ed[2][4][NN];

    const int t = threadIdx.x;
    const int lane = t & 63, wave = t >> 6;
    const long b0 = (long)blockIdx.x * 2;

    // ---- stage x: fp32 -> bf16 hi/lo, swizzled A-fragment layout ----
    {
        const float4* src = (const float4*)(x_in + b0 * NN * FIN);
        #pragma unroll
        for (int j = 0; j < 3; ++j) {
            int p = j * 256 + t;                 // float4 index 0..767
            float4 v = src[p];
            int row = p >> 5, cb = (p & 31) * 4;
            int m = row >> 4, r15 = row & 15;
            int ks = cb >> 5, aks = (cb >> 3) & 3, jj = cb & 7;
            int us = swz((ks * 2 + m) * 64 + aks * 16 + r15);
            ushort4 h, l;
            h.x = f2bf(v.x); l.x = f2bf(v.x - bf2f(h.x));
            h.y = f2bf(v.y); l.y = f2bf(v.y - bf2f(h.y));
            h.z = f2bf(v.z); l.z = f2bf(v.z - bf2f(h.z));
            h.w = f2bf(v.w); l.w = f2bf(v.w - bf2f(h.w));
            *(ushort4*)&s_xfh[us * 8 + jj] = h;
            *(ushort4*)&s_xfl[us * 8 + jj] = l;
        }
        // NOTE: no zero-pad of rows 24..31 — garbage A rows only affect
        // discarded C rows 24..31 (row<24 store guard below).
    }
    __syncthreads();

    // ---- Phase A: h1 = x @ W1 via MFMA (M=32 padded, N=256, K=128) ----
    {
        bf16x8 ah[2][4], al[2][4];
        #pragma unroll
        for (int m = 0; m < 2; ++m)
            #pragma unroll
            for (int ks = 0; ks < 4; ++ks) {
                int us = swz((ks * 2 + m) * 64 + lane);
                ah[m][ks] = *(const bf16x8*)&s_xfh[us * 8];
                al[m][ks] = *(const bf16x8*)&s_xfl[us * 8];
            }
        __syncthreads();   // x reads done -> h1f may overlay

        #pragma unroll
        for (int nti = 0; nti < 4; ++nti) {
            const int nt = wave * 4 + nti;
            bf16x8 bh[4], bl[4];
            #pragma unroll
            for (int ks = 0; ks < 4; ++ks) {
                int off = ((nt * 4 + ks) * 64 + lane) * 8;
                bh[ks] = *(const bf16x8*)&wtab[WS_W1H + off];
                bl[ks] = *(const bf16x8*)&wtab[WS_W1L + off];
            }
            f32x4 acc[2] = { {0.f,0.f,0.f,0.f}, {0.f,0.f,0.f,0.f} };
            #pragma unroll
            for (int ks = 0; ks < 4; ++ks)
                #pragma unroll
                for (int m = 0; m < 2; ++m) {
                    acc[m] = __builtin_amdgcn_mfma_f32_16x16x32_bf16(ah[m][ks], bh[ks], acc[m], 0, 0, 0);
                    acc[m] = __builtin_amdgcn_mfma_f32_16x16x32_bf16(ah[m][ks], bl[ks], acc[m], 0, 0, 0);
                    acc[m] = __builtin_amdgcn_mfma_f32_16x16x32_bf16(al[m][ks], bh[ks], acc[m], 0, 0, 0);
                }
            const int ccol = nt * 16 + (lane & 15);
            #pragma unroll
            for (int m = 0; m < 2; ++m)
                #pragma unroll
                for (int r = 0; r < 4; ++r) {
                    int row = m * 16 + (lane >> 4) * 4 + r;
                    if (row < 24) s_h1f[row * 268 + ccol] = acc[m][r];
                }
        }
    }
    __syncthreads();

    // ---- Phase B: es/ed logits (192 tasks), fp32 reads ----
    if (t < 192) {
        int tmp = t;
        const int n = tmp % NN; tmp /= NN;
        const int h = tmp & 3; tmp >>= 2;
        const int sflag = tmp & 1;
        const int g = tmp >> 1;
        const float* att = (sflag ? adst1 : asrc1) + h * DD;
        const float* row = s_h1f + (g * NN + n) * 268 + h * DD;
        float sum = 0.f;
        #pragma unroll
        for (int it = 0; it < 8; ++it) {
            const int ch = ((it + t) & 7) * 8;   // rotated chunks
            float4 h0 = *(const float4*)&row[ch];
            float4 h1v = *(const float4*)&row[ch + 4];
            float4 a0 = *(const float4*)&att[ch];
            float4 a1 = *(const float4*)&att[ch + 4];
            sum += h0.x*a0.x + h0.y*a0.y + h0.z*a0.z + h0.w*a0.w
                 + h1v.x*a1.x + h1v.y*a1.y + h1v.z*a1.z + h1v.w*a1.w;
        }
        if (sflag) s_ed[g][h][n] = sum; else s_es[g][h][n] = sum;
    }
    __syncthreads();

    // ---- Phase C: softmax over sources (96 tasks) ----
    if (t < 96) {
        const int i = t % NN;
        const int h = (t / NN) & 3;
        const int g = t / (NN * 4);
        const float edv = s_ed[g][h][i];
        float l[NN];
        float m = -3.4e38f;
        #pragma unroll
        for (int j = 0; j < NN; ++j) {
            float v = edv + s_es[g][h][j];
            v = (v >= 0.f) ? v : NEG * v;
            l[j] = v; m = fmaxf(m, v);
        }
        float s = 0.f;
        #pragma unroll
        for (int j = 0; j < NN; ++j) { float p = __expf(l[j] - m); l[j] = p; s += p; }
        const float inv = 1.f / s;
        #pragma unroll
        for (int j = 0; j < NN; ++j) s_alpha[g][h][i][j] = l[j] * inv;
    }
    __syncthreads();

    // ---- Phase D: x2 = elu(alpha @ h1 + b1) -> regs -> swizzled bf16 frags ----
    {
        const int c = t;
        const int hh = c >> 6;
        const float bias = b1[c];
        float x2v[2][NN];
        #pragma unroll
        for (int g = 0; g < 2; ++g) {
            float hcol[NN];
            #pragma unroll
            for (int j = 0; j < NN; ++j) hcol[j] = s_h1f[(g * NN + j) * 268 + c];
            #pragma unroll
            for (int i = 0; i < NN; ++i) {
                const float4* ar = (const float4*)&s_alpha[g][hh][i][0];
                float4 q0 = ar[0], q1 = ar[1], q2 = ar[2];
                float o = q0.x*hcol[0] + q0.y*hcol[1] + q0.z*hcol[2] + q0.w*hcol[3]
                        + q1.x*hcol[4] + q1.y*hcol[5] + q1.z*hcol[6] + q1.w*hcol[7]
                        + q2.x*hcol[8] + q2.y*hcol[9] + q2.z*hcol[10] + q2.w*hcol[11];
                o += bias;
                x2v[g][i] = (o > 0.f) ? o : (__expf(o) - 1.f);
            }
        }
        __syncthreads();   // all h1f reads done -> x2 frags may overlay

        const int ks_c = c >> 5, aks_c = (c >> 3) & 3, j_c = c & 7;
        #pragma unroll
        for (int g = 0; g < 2; ++g)
            #pragma unroll
            for (int i = 0; i < NN; ++i) {
                int row = g * NN + i;
                int us = swz((ks_c * 2 + (row >> 4)) * 64 + aks_c * 16 + (row & 15));
                float v = x2v[g][i];
                u16 hi = f2bf(v);
                s_x2h[us * 8 + j_c] = hi;
                s_x2l[us * 8 + j_c] = f2bf(v - bf2f(hi));
            }
        // (no pad-row zeroing — see note in stage)
    }
    __syncthreads();

    // ---- Phase E: h2 = x2 @ W2 via MFMA (M=32 padded, N=64, K=256) ----
    {
        f32x4 acc[2] = { {0.f,0.f,0.f,0.f}, {0.f,0.f,0.f,0.f} };
        #pragma unroll
        for (int ks = 0; ks < 8; ++ks) {
            int woff = ((wave * 8 + ks) * 64 + lane) * 8;
            bf16x8 bh = *(const bf16x8*)&wtab[WS_W2H + woff];
            bf16x8 bl = *(const bf16x8*)&wtab[WS_W2L + woff];
            #pragma unroll
            for (int m = 0; m < 2; ++m) {
                int us = swz((ks * 2 + m) * 64 + lane);
                bf16x8 ah = *(const bf16x8*)&s_x2h[us * 8];
                bf16x8 al = *(const bf16x8*)&s_x2l[us * 8];
                acc[m] = __builtin_amdgcn_mfma_f32_16x16x32_bf16(ah, bh, acc[m], 0, 0, 0);
                acc[m] = __builtin_amdgcn_mfma_f32_16x16x32_bf16(ah, bl, acc[m], 0, 0, 0);
                acc[m] = __builtin_amdgcn_mfma_f32_16x16x32_bf16(al, bh, acc[m], 0, 0, 0);
            }
        }
        __syncthreads();   // x2-frag reads done -> h2 may overlay union
        const int ccol = wave * 16 + (lane & 15);
        #pragma unroll
        for (int m = 0; m < 2; ++m)
            #pragma unroll
            for (int r = 0; r < 4; ++r) {
                int row = m * 16 + (lane >> 4) * 4 + r;
                if (row < 24) s_h2[row * 68 + ccol] = acc[m][r];
            }
    }
    __syncthreads();

    // ---- Phase F: layer-2 logits + softmax ----
    if (t < 48) {
        const int n = t % NN;
        const int sflag = (t / NN) & 1;
        const int g = t / (NN * 2);
        const float* att = sflag ? adst2 : asrc2;
        const float* row = s_h2 + (g * NN + n) * 68;
        float sum = 0.f;
        #pragma unroll
        for (int it = 0; it < 16; ++it) {
            const int dch = ((it + t) & 15) * 4;
            float4 hv = *(const float4*)&row[dch];
            float4 av = *(const float4*)&att[dch];
            sum += hv.x * av.x + hv.y * av.y + hv.z * av.z + hv.w * av.w;
        }
        if (sflag) s_ed2[g * NN + n] = sum; else s_es2[g * NN + n] = sum;
    }
    __syncthreads();
    if (t < 24) {
        const int i = t % NN;
        const int g = t / NN;
        const float edv = s_ed2[g * NN + i];
        float l[NN];
        float m = -3.4e38f;
        #pragma unroll
        for (int j = 0; j < NN; ++j) {
            float v = edv + s_es2[g * NN + j];
            v = (v >= 0.f) ? v : NEG * v;
            l[j] = v; m = fmaxf(m, v);
        }
        float s = 0.f;
        #pragma unroll
        for (int j = 0; j < NN; ++j) { float p = __expf(l[j] - m); l[j] = p; s += p; }
        const float inv = 1.f / s;
        #pragma unroll
        for (int j = 0; j < NN; ++j) s_al2[(g * NN + i) * NN + j] = l[j] * inv;
    }
    __syncthreads();

    // ---- Phase G: out2 = elu(alpha2 @ h2 + b2), mean-pool ----
    if (t < 128) {
        const int g = t >> 6;
        const int d = t & 63;
        float hcol[NN];
        #pragma unroll
        for (int j = 0; j < NN; ++j) hcol[j] = s_h2[(g * NN + j) * 68 + d];
        const float bias = b2[d];
        float gsum = 0.f;
        #pragma unroll
        for (int i = 0; i < NN; ++i) {
            const float4* ar = (const float4*)&s_al2[(g * NN + i) * NN];
            float4 q0 = ar[0], q1 = ar[1], q2 = ar[2];
            float o = q0.x*hcol[0] + q0.y*hcol[1] + q0.z*hcol[2] + q0.w*hcol[3]
                    + q1.x*hcol[4] + q1.y*hcol[5] + q1.z*hcol[6] + q1.w*hcol[7]
                    + q2.x*hcol[8] + q2.y*hcol[9] + q2.z*hcol[10] + q2.w*hcol[11];
            o += bias;
            o = (o > 0.f) ? o : (__expf(o) - 1.f);
            gsum += o;
        }
        s_gm[g * DD + d] = gsum * (1.f / 12.f);
    }
    __syncthreads();

    // ---- Phase H: classifier ----
    if (t < 64) {
        const int g = t >> 5;
        const int m = t & 31;
        float sum = bc1[m];
        #pragma unroll
        for (int d = 0; d < DD; ++d) sum = fmaf(s_gm[g * DD + d], Wc1[d * 32 + m], sum);
        s_hc[g * 32 + m] = (sum > 0.f) ? sum : 0.f;
    }
    __syncthreads();
    if (t < 2) {
        float sum = bc2[0];
        #pragma unroll
        for (int m = 0; m < 32; ++m) sum = fmaf(s_hc[t * 32 + m], Wc2[m], sum);
        out[b0 + t] = sum;
    }
}

extern "C" void kernel_launch(void* const* d_in, const int* in_sizes, int n_in,
                              void* d_out, int out_size, void* d_ws, size_t ws_size,
                              hipStream_t stream) {
    const float* x     = (const float*)d_in[0];
    const float* W1    = (const float*)d_in[1];
    const float* asrc1 = (const float*)d_in[2];
    const float* adst1 = (const float*)d_in[3];
    const float* b1    = (const float*)d_in[4];
    const float* W2    = (const float*)d_in[5];
    const float* asrc2 = (const float*)d_in[6];
    const float* adst2 = (const float*)d_in[7];
    const float* b2    = (const float*)d_in[8];
    const float* Wc1   = (const float*)d_in[9];
    const float* bc1   = (const float*)d_in[10];
    const float* Wc2   = (const float*)d_in[11];
    const float* bc2   = (const float*)d_in[12];
    float* outp = (float*)d_out;

    const int B = in_sizes[0] / (NN * FIN);   // 32768
    u16* wtab = (u16*)d_ws;                   // needs 196608 B of ws

    hipLaunchKernelGGL(prep_weights, dim3(192), dim3(256), 0, stream, W1, W2, wtab);
    hipLaunchKernelGGL(gat_fused, dim3(B / 2), dim3(256), 0, stream,
                       x, wtab, asrc1, adst1, b1, asrc2, adst2, b2,
                       Wc1, bc1, Wc2, bc2, outp);
}